// Round 12
// baseline (1472.030 us; speedup 1.0000x reference)
//
#include <hip/hip_runtime.h>
#include <hip/hip_fp16.h>
#include <stdint.h>

typedef unsigned int uint;
typedef unsigned short ushort;
typedef unsigned char uchar;

#define NB 2048
#define NW 64
#define NF 128
#define NH 128

typedef __attribute__((ext_vector_type(8))) short s8v;
typedef __attribute__((ext_vector_type(8))) _Float16 h8v;
typedef __attribute__((ext_vector_type(4))) float f4v;
typedef __attribute__((ext_vector_type(2))) float f2v;
typedef __attribute__((ext_vector_type(2))) _Float16 h2v;
typedef __attribute__((ext_vector_type(2))) __fp16 p2v;

#define MFMA16(a, b, c) __builtin_amdgcn_mfma_f32_16x16x32_bf16((a), (b), (c), 0, 0, 0)
#define MFMAH(a, b, c)  __builtin_amdgcn_mfma_f32_16x16x32_f16((a), (b), (c), 0, 0, 0)
#define MFMA8(a, b, c)  __builtin_amdgcn_mfma_f32_16x16x32_fp8_fp8((a), (b), (c), 0, 0, 0)

union H8 { h8v v; __half2 h2[4]; h2v hx[4]; p2v px[4]; uint4 u4; uint2 u2[2]; ushort us[8]; };
union U8 { uint2 u2; long v; };

__device__ __forceinline__ float bfl(uint u){ return __uint_as_float(u << 16); }
__device__ __forceinline__ float bfh(uint u){ return __uint_as_float(u & 0xffff0000u); }
__device__ __forceinline__ float bf2f(ushort s){ return __uint_as_float(((uint)s) << 16); }
__device__ __forceinline__ ushort f2bf(float f){
  uint u = __float_as_uint(f);
  u += 0x7fffu + ((u >> 16) & 1u);
  return (ushort)(u >> 16);
}

__device__ __forceinline__ float fast_tanh(float x){
  float e = __expf(x + x);
  return 1.f - 2.f * __builtin_amdgcn_rcpf(e + 1.f);
}
__device__ __forceinline__ float fast_sig(float x){
  return __builtin_amdgcn_rcpf(1.f + __expf(-x));
}
// s' = f16(exp(2x - 1))  (pairs with E' = fp8(exp(2u + 1)))
__device__ __forceinline__ ushort expo_hm(float x){
  return __half_as_ushort(__float2half(__expf(x + x - 1.f)));
}
// E' = fp8 e4m3 of exp(2x + 1)
__device__ __forceinline__ uchar expo_fp8(float x){
  float e = __expf(x + x + 1.f);
  return (uchar)(__builtin_amdgcn_cvt_pk_fp8_f32(e, e, 0, false) & 0xff);
}
// pack 4 f32 -> 4 fp8 e4m3 bytes
__device__ __forceinline__ uint f2fp8x4(float a, float b, float c, float d){
  uint u = (uint)__builtin_amdgcn_cvt_pk_fp8_f32(a, b, 0, false);
  u = (uint)__builtin_amdgcn_cvt_pk_fp8_f32(c, d, (int)u, true);
  return u;
}
// decode 8 fp8 -> 8 f16
__device__ __forceinline__ H8 fp8x8_to_h8(uint2 ev){
  H8 r;
  f2v a = __builtin_amdgcn_cvt_pk_f32_fp8((int)ev.x, false);
  f2v b = __builtin_amdgcn_cvt_pk_f32_fp8((int)ev.x, true);
  f2v c = __builtin_amdgcn_cvt_pk_f32_fp8((int)ev.y, false);
  f2v d = __builtin_amdgcn_cvt_pk_f32_fp8((int)ev.y, true);
  r.px[0] = __builtin_amdgcn_cvt_pkrtz(a.x, a.y);
  r.px[1] = __builtin_amdgcn_cvt_pkrtz(b.x, b.y);
  r.px[2] = __builtin_amdgcn_cvt_pkrtz(c.x, c.y);
  r.px[3] = __builtin_amdgcn_cvt_pkrtz(d.x, d.y);
  return r;
}

__device__ __forceinline__ s8v packW(const float* p){
  s8v r;
  #pragma unroll
  for (int i = 0; i < 8; ++i) r[i] = (short)f2bf(p[i]);
  return r;
}

// ------- E_enc8: fp8(exp(2*upre + 1)) in coalesced layout [b][ft8][kb2][lane64][8B] -------
__global__ __launch_bounds__(256) void k_upre(const float* __restrict__ X,
                                              const float* __restrict__ iaW1,
                                              uchar* __restrict__ E8){
  __shared__ __align__(16) float sXT[128*68];
  __shared__ __align__(16) uchar sOut[8192];
  const int tid = threadIdx.x, lane = tid & 63, wave = tid >> 6, g = lane >> 4;
  int b = blockIdx.x;
  const float* Xb = X + (size_t)b*NW*NF;
  for (int i = tid; i < NW*NF; i += 256){
    int j = i >> 7, f = i & 127;
    sXT[f*68 + j] = Xb[i];
  }
  s8v bw[2];
  {
    int w = wave*16 + (lane & 15);
    #pragma unroll
    for (int kb = 0; kb < 2; ++kb) bw[kb] = packW(iaW1 + w*320 + kb*32 + g*8);
  }
  __syncthreads();
  int w = wave*16 + (lane & 15);
  #pragma unroll
  for (int mt = 0; mt < 8; ++mt){
    int f0 = mt*16 + (lane & 15);
    f4v acc = {0.f,0.f,0.f,0.f};
    #pragma unroll
    for (int kb = 0; kb < 2; ++kb){
      const float* p = &sXT[f0*68 + kb*32 + g*8];
      s8v a;
      #pragma unroll
      for (int i = 0; i < 8; ++i) a[i] = (short)f2bf(p[i]);
      acc = MFMA16(a, bw[kb], acc);
    }
    int fr = mt*16 + g*4;
    #pragma unroll
    for (int j = 0; j < 4; ++j){
      int f = fr + j;
      sOut[mt*1024 + (w>>5)*512 + (((w>>3)&3)*16 + (f&15))*8 + (w&7)] = expo_fp8(acc[j]);
    }
  }
  __syncthreads();
  uchar* outb = E8 + (size_t)b*8192;
  *(uint4*)(outb + tid*32)      = *(const uint4*)(sOut + tid*32);
  *(uint4*)(outb + tid*32 + 16) = *(const uint4*)(sOut + tid*32 + 16);
}

// ------- E_dec8: fp8(exp(2*vpre + 1)) layout [b][wt4][kb4][lane64][8B]; HsT8 fp8(16*Hs^T) -------
__global__ __launch_bounds__(256) void k_vpre(const ushort* __restrict__ Hsb,
                                              const float* __restrict__ taW1,
                                              uchar* __restrict__ E8,
                                              uchar* __restrict__ HsT8){
  __shared__ __align__(16) ushort sH[64*136];
  __shared__ __align__(16) uchar sOut[8192];
  const int tid = threadIdx.x, lane = tid & 63, wave = tid >> 6, g = lane >> 4;
  int b = blockIdx.x;
  const ushort* Hb = Hsb + (size_t)b*NW*NH;
  for (int i = tid; i < 1024; i += 256){
    int w = i >> 4, c = i & 15;
    *(uint4*)&sH[w*136 + c*8] = *(const uint4*)(Hb + i*8);
  }
  s8v bw[2][4];
  #pragma unroll
  for (int nt = 0; nt < 2; ++nt){
    int h = wave*32 + nt*16 + (lane & 15);
    #pragma unroll
    for (int kb = 0; kb < 4; ++kb)
      bw[nt][kb] = packW(taW1 + h*384 + kb*32 + g*8);
  }
  __syncthreads();
  // HsT8[h][w] = fp8(16*Hs^T)
  uchar* ho = HsT8 + (size_t)b*NH*NW;
  for (int k = 0; k < 8; ++k){
    int s = tid + 256*k;
    int h = s >> 4, w0 = (s & 15)*4;
    float f0 = bf2f(sH[(w0+0)*136 + h])*16.f;
    float f1 = bf2f(sH[(w0+1)*136 + h])*16.f;
    float f2 = bf2f(sH[(w0+2)*136 + h])*16.f;
    float f3 = bf2f(sH[(w0+3)*136 + h])*16.f;
    *(uint*)(ho + h*64 + w0) = f2fp8x4(f0, f1, f2, f3);
  }
  #pragma unroll
  for (int mt = 0; mt < 4; ++mt){
    s8v af[4];
    #pragma unroll
    for (int kb = 0; kb < 4; ++kb)
      af[kb] = *(const s8v*)&sH[(mt*16 + (lane&15))*136 + kb*32 + g*8];
    #pragma unroll
    for (int nt = 0; nt < 2; ++nt){
      f4v acc = {0.f,0.f,0.f,0.f};
      #pragma unroll
      for (int kb = 0; kb < 4; ++kb) acc = MFMA16(af[kb], bw[nt][kb], acc);
      int h = wave*32 + nt*16 + (lane&15);
      int wr = mt*16 + g*4;
      #pragma unroll
      for (int j = 0; j < 4; ++j){
        int w2_ = wr + j;
        sOut[(w2_>>4)*2048 + (h>>5)*512 + (((h>>3)&3)*16 + (w2_&15))*8 + (h&7)] = expo_fp8(acc[j]);
      }
    }
  }
  __syncthreads();
  uchar* outb = E8 + (size_t)b*8192;
  *(uint4*)(outb + tid*32)      = *(const uint4*)(sOut + tid*32);
  *(uint4*)(outb + tid*32 + 16) = *(const uint4*)(sOut + tid*32 + 16);
}

// =========================== encoder: 512 blocks x 4 batches ===========================
// LDS ~15KB -> 2 blocks/CU if regs permit
__global__ __launch_bounds__(512, 2) void k_enc(
    const float* __restrict__ X, const float* __restrict__ iaW1,
    const float* __restrict__ iab1, const float* __restrict__ iaW2,
    const float* __restrict__ encWih, const float* __restrict__ encWhh,
    const float* __restrict__ encbih, const float* __restrict__ encbhh,
    const uchar* __restrict__ Eenc8, ushort* __restrict__ Hsb){
  __shared__ __align__(16) ushort sAB[16*392];   // c(0-127)|h(128-255)|xt(256-383), stride 392
  __shared__ __align__(16) ushort uhc_h[4*64];   // exp(2*uhc-1) f16
  __shared__ __align__(16) float  xrow[4*128];
  __shared__ float sum_s[8];

  const int tid = threadIdx.x, lane = tid & 63, wave = tid >> 6, g = lane >> 4;
  const int bbase = blockIdx.x * 4;
  const int bb = wave & 3, half = wave >> 2;
  const int n16 = wave*16 + (lane & 15);

  for (int i = tid; i < 16*392; i += 512) sAB[i] = 0;
  float bias_r[4];
  #pragma unroll
  for (int gg = 0; gg < 4; ++gg)
    bias_r[gg] = encbih[gg*128 + n16] + encbhh[gg*128 + n16];
  float b1_r = iab1[n16 & 63];
  float c_r[4] = {0.f, 0.f, 0.f, 0.f};
  s8v bwC[4][8];
  #pragma unroll
  for (int gg = 0; gg < 4; ++gg){
    int j = gg*128 + n16;
    #pragma unroll
    for (int kc = 0; kc < 8; ++kc){
      const float* p = (kc < 4) ? (encWih + j*128 + kc*32) : (encWhh + j*128 + (kc-4)*32);
      bwC[gg][kc] = packW(p + g*8);
    }
  }
  s8v bwA[8];
  if (wave < 4){
    #pragma unroll
    for (int kc = 0; kc < 8; ++kc){
      int col = (kc < 4) ? (192 + kc*32) : (64 + (kc-4)*32);
      bwA[kc] = packW(iaW1 + n16*320 + col + g*8);
    }
  }
  H8 w2f[2];
  #pragma unroll
  for (int kb = 0; kb < 2; ++kb)
    #pragma unroll
    for (int i = 0; i < 8; ++i)
      w2f[kb].v[i] = (_Float16)iaW2[kb*32 + g*8 + i];
  if (wave < 4){
    const float* Xr = X + ((size_t)(bbase + wave)*NW + 0)*NF;
    xrow[wave*128 + lane] = Xr[lane];
    xrow[wave*128 + 64 + lane] = Xr[64 + lane];
  }
  __syncthreads();

  const uchar* Eb = Eenc8 + (size_t)(bbase + bb)*8192;

  for (int t = 0; t < NW; ++t){
    float xn0 = 0.f, xn1 = 0.f;
    if (wave < 4){
      int tn = (t + 1) & 63;
      const float* Xr = X + ((size_t)(bbase + wave)*NW + tn)*NF;
      xn0 = Xr[lane];
      xn1 = Xr[64 + lane];
    }
    // ---- A: read [c|h]; waves 0-3: uhc via MFMA ----
    s8v aT[8];
    #pragma unroll
    for (int kc = 0; kc < 8; ++kc)
      aT[kc] = *(const s8v*)((const char*)sAB + (lane&15)*784 + kc*64 + g*16);
    if (wave < 4){
      f4v acc = {0.f,0.f,0.f,0.f};
      #pragma unroll
      for (int kc = 0; kc < 8; ++kc) acc = MFMA16(aT[kc], bwA[kc], acc);
      if (lane < 16){
        #pragma unroll
        for (int j = 0; j < 4; ++j) uhc_h[j*64 + n16] = expo_hm(acc[j] + b1_r);
      }
    }
    __syncthreads();  // 1

    // ---- B (split: half does 4 ft): M via fp8-global + f16 rcp + MFMAH ----
    float xs[4][4];
    {
      H8 sv[2];
      #pragma unroll
      for (int kb = 0; kb < 2; ++kb)
        sv[kb].u4 = *(const uint4*)((const char*)uhc_h + bb*128 + kb*64 + g*16);
      __half2 one2 = __float2half2_rn(1.f);
      float ssum = 0.f;
      #pragma unroll
      for (int fi4 = 0; fi4 < 4; ++fi4){
        int ft = half*4 + fi4;
        f4v acc = {0.f,0.f,0.f,0.f};
        #pragma unroll
        for (int kb = 0; kb < 2; ++kb){
          uint2 ev = *(const uint2*)(Eb + ft*1024 + kb*512 + lane*8);
          H8 e = fp8x8_to_h8(ev);
          H8 a;
          #pragma unroll
          for (int q = 0; q < 4; ++q) a.h2[q] = h2rcp(__hfma2(e.h2[q], sv[kb].h2[q], one2));
          acc = MFMAH(a.v, w2f[kb].v, acc);
        }
        #pragma unroll
        for (int r = 0; r < 4; ++r){ float x = __expf(-2.f*acc[r]); xs[fi4][r] = x; ssum += x; }
      }
      ssum += __shfl_xor(ssum, 16, 64);
      ssum += __shfl_xor(ssum, 32, 64);
      if (lane == 0) sum_s[wave] = ssum;
    }
    __syncthreads();  // 1.5 (sum exchange)
    {
      float inv = __builtin_amdgcn_rcpf(sum_s[bb] + sum_s[bb+4]);
      if ((lane & 15) == 0){
        #pragma unroll
        for (int fi4 = 0; fi4 < 4; ++fi4){
          int f0 = (half*4 + fi4)*16 + g*4;
          float4 Xv = *(const float4*)&xrow[bb*128 + f0];
          uint lo = (uint)f2bf(xs[fi4][0]*inv*Xv.x) | ((uint)f2bf(xs[fi4][1]*inv*Xv.y) << 16);
          uint hi = (uint)f2bf(xs[fi4][2]*inv*Xv.z) | ((uint)f2bf(xs[fi4][3]*inv*Xv.w) << 16);
          *(uint2*)((char*)sAB + bb*784 + 512 + f0*2) = make_uint2(lo, hi);
        }
      }
    }
    __syncthreads();  // 2

    // ---- gates via MFMA; in-wave LSTM update (state in lanes<16, batches 0-3) ----
    {
      s8v aX[4];
      #pragma unroll
      for (int kc = 0; kc < 4; ++kc)
        aX[kc] = *(const s8v*)((const char*)sAB + (lane&15)*784 + 512 + kc*64 + g*16);
      f4v acc[4];
      #pragma unroll
      for (int gg = 0; gg < 4; ++gg) acc[gg] = (f4v){0.f,0.f,0.f,0.f};
      #pragma unroll
      for (int kc = 0; kc < 8; ++kc){
        s8v af = (kc < 4) ? aX[kc] : aT[kc];
        #pragma unroll
        for (int gg = 0; gg < 4; ++gg) acc[gg] = MFMA16(af, bwC[gg][kc], acc[gg]);
      }
      if (lane < 16){
        #pragma unroll
        for (int j = 0; j < 4; ++j){
          float gi = acc[0][j] + bias_r[0];
          float gf = acc[1][j] + bias_r[1];
          float gg2 = acc[2][j] + bias_r[2];
          float go = acc[3][j] + bias_r[3];
          float cold = c_r[j];
          float cn = fast_sig(gf)*cold + fast_sig(gi)*fast_tanh(gg2);
          float hn = fast_sig(go)*fast_tanh(cn);
          c_r[j] = cn;
          sAB[j*392 + n16] = f2bf(cn);
          sAB[j*392 + 128 + n16] = f2bf(hn);
          Hsb[((size_t)(bbase + j)*NW + t)*NH + n16] = f2bf(hn);
        }
      }
      if (wave < 4){
        xrow[wave*128 + lane] = xn0;
        xrow[wave*128 + 64 + lane] = xn1;
      }
    }
    __syncthreads();  // 3
  }
}

// =========================== decoder: 512 blocks x 4 batches ===========================
__global__ __launch_bounds__(512, 2) void k_dec(
    const float* __restrict__ taW1, const float* __restrict__ tab1,
    const float* __restrict__ taW2,
    const float* __restrict__ decWih, const float* __restrict__ decWhh,
    const float* __restrict__ decbih, const float* __restrict__ decbhh,
    const float* __restrict__ l1W, const float* __restrict__ l1b,
    const float* __restrict__ l2W, const float* __restrict__ l2b,
    const float* __restrict__ l3W, const float* __restrict__ l3b,
    const uchar* __restrict__ Edec8, const uchar* __restrict__ HsT8,
    float* __restrict__ out){
  __shared__ __align__(16) ushort sAB[16*264];   // [d|ds] bf16 (rows 0-3 real)
  __shared__ __align__(16) ushort sCT[16*136];   // ct bf16 (rows 0-3 real, rest zero)
  __shared__ __align__(16) float  sCTp[2][4][128];
  __shared__ __align__(16) ushort vd_h[4*128];   // exp(2*vd-1) f16
  __shared__ __align__(16) uchar  lb8[4*64];     // beta*16/s_half fp8
  __shared__ __align__(16) ushort sW2h[128];
  __shared__ __align__(16) float  op_s[8][4];
  __shared__ float ps[8], sum_s[8];

  const int tid = threadIdx.x, lane = tid & 63, wave = tid >> 6, g = lane >> 4;
  const int bbase = blockIdx.x * 4;
  const int bb = wave & 3, half = wave >> 2;
  const int n16 = wave*16 + (lane & 15);

  for (int i = tid; i < 16*264; i += 512) sAB[i] = 0;
  for (int i = tid; i < 16*136; i += 512) sCT[i] = 0;
  if (tid < 128) sW2h[tid] = __half_as_ushort(__float2half(taW2[tid]));
  if (tid < 32) ((float*)op_s)[tid] = 0.f;
  float bias_r[4], wih_r[4];
  #pragma unroll
  for (int gg = 0; gg < 4; ++gg){
    bias_r[gg] = decbih[gg*128 + n16] + decbhh[gg*128 + n16];
    wih_r[gg]  = decWih[gg*128 + n16];
  }
  float tab1_r = tab1[n16];
  float l2b_r  = l2b[n16];
  float l3w_r  = l3W[n16];
  float l1w0 = l1W[0], l1b0 = l1b[0], l3b0 = l3b[0];
  float cds_r[4] = {0.f, 0.f, 0.f, 0.f};
  s8v bwA[8];
  #pragma unroll
  for (int kc = 0; kc < 8; ++kc)
    bwA[kc] = packW(taW1 + n16*384 + 128 + kc*32 + g*8);
  s8v bwD[4][4];
  #pragma unroll
  for (int gg = 0; gg < 4; ++gg){
    int j = gg*128 + n16;
    #pragma unroll
    for (int kc = 0; kc < 4; ++kc)
      bwD[gg][kc] = packW(decWhh + j*128 + kc*32 + g*8);
  }
  s8v bwF[8];
  #pragma unroll
  for (int kc = 0; kc < 8; ++kc)
    bwF[kc] = packW(l2W + n16*256 + kc*32 + g*8);
  float l1w[8];
  #pragma unroll
  for (int ht = 0; ht < 8; ++ht) l1w[ht] = l1W[1 + ht*16 + (lane & 15)];
  __syncthreads();

  const uchar* Eb  = Edec8 + (size_t)(bbase + bb)*8192;
  const uchar* hb8 = HsT8 + (size_t)(bbase + bb)*NH*NW;

  for (int t = 0; t < NW; ++t){
    // ---- A: vd via MFMA from [d|ds] ----
    s8v aT[8];
    #pragma unroll
    for (int kc = 0; kc < 8; ++kc)
      aT[kc] = *(const s8v*)((const char*)sAB + (lane&15)*528 + kc*64 + g*16);
    {
      f4v acc = {0.f,0.f,0.f,0.f};
      #pragma unroll
      for (int kc = 0; kc < 8; ++kc) acc = MFMA16(aT[kc], bwA[kc], acc);
      if (lane < 16){
        #pragma unroll
        for (int j = 0; j < 4; ++j) vd_h[j*128 + n16] = expo_hm(acc[j] + tab1_r);
      }
    }
    __syncthreads();  // 1

    // ---- B+C split: half owns wt {2h,2h+1} (w range half*32..+31) ----
    {
      U8 hbf[8];
      #pragma unroll
      for (int ht = 0; ht < 8; ++ht){
        int h = ht*16 + (lane & 15);
        hbf[ht].u2 = *(const uint2*)(hb8 + h*64 + half*32 + g*8);
      }
      H8 sv[4];
      #pragma unroll
      for (int kb = 0; kb < 4; ++kb)
        sv[kb].u4 = *(const uint4*)((const char*)vd_h + bb*256 + kb*64 + g*16);
      __half2 one2 = __float2half2_rn(1.f);
      float xs[2][4]; float ssum = 0.f;
      #pragma unroll
      for (int wi2 = 0; wi2 < 2; ++wi2){
        int wt = half*2 + wi2;
        f4v acc = {0.f,0.f,0.f,0.f};
        #pragma unroll
        for (int kb = 0; kb < 4; ++kb){
          uint2 ev = *(const uint2*)(Eb + wt*2048 + kb*512 + lane*8);
          H8 e = fp8x8_to_h8(ev);
          H8 a, wv;
          wv.u4 = *(const uint4*)&sW2h[kb*32 + g*8];
          #pragma unroll
          for (int q = 0; q < 4; ++q) a.h2[q] = h2rcp(__hfma2(e.h2[q], sv[kb].h2[q], one2));
          acc = MFMAH(a.v, wv.v, acc);
        }
        #pragma unroll
        for (int r = 0; r < 4; ++r){ float x = __expf(-2.f*acc[r]); xs[wi2][r] = x; ssum += x; }
      }
      ssum += __shfl_xor(ssum, 16, 64);
      ssum += __shfl_xor(ssum, 32, 64);
      if (lane == 0) sum_s[wave] = ssum;
      float inv16o = 16.f * __builtin_amdgcn_rcpf(ssum);
      if ((lane & 15) == 0){
        #pragma unroll
        for (int wi2 = 0; wi2 < 2; ++wi2){
          int w0 = (half*2 + wi2)*16 + g*4;
          *(uint*)(lb8 + bb*64 + w0) =
            f2fp8x4(xs[wi2][0]*inv16o, xs[wi2][1]*inv16o, xs[wi2][2]*inv16o, xs[wi2][3]*inv16o);
        }
      }
      // same-wave: own-half beta as fp8 A-frag
      U8 ba;
      ba.u2 = *(const uint2*)(lb8 + bb*64 + half*32 + g*8);
      float p = 0.f;
      #pragma unroll
      for (int ht = 0; ht < 8; ++ht){
        f4v acc = {0.f,0.f,0.f,0.f};
        acc = MFMA8(ba.v, hbf[ht].v, acc);
        float ctp = acc[0];
        if (lane < 16) sCTp[half][bb][ht*16 + (lane&15)] = ctp;
        p += l1w[ht] * ctp;
      }
      p += __shfl_xor(p, 1, 64);
      p += __shfl_xor(p, 2, 64);
      p += __shfl_xor(p, 4, 64);
      p += __shfl_xor(p, 8, 64);
      if (lane == 0) ps[wave] = p;
    }
    __syncthreads();  // 2

    // ---- D: ct recombine, gates via MFMA, in-wave update ----
    {
      int b2 = tid >> 7, h = tid & 127;
      float s0 = sum_s[b2], s1 = sum_s[b2+4];
      float invt = __builtin_amdgcn_rcpf((s0 + s1) * 256.f);
      sCT[b2*136 + h] = f2bf((s0*sCTp[0][b2][h] + s1*sCTp[1][b2][h]) * invt);
    }
    {
      f4v g4[4];
      #pragma unroll
      for (int gg = 0; gg < 4; ++gg) g4[gg] = (f4v){0.f,0.f,0.f,0.f};
      #pragma unroll
      for (int kc = 0; kc < 4; ++kc){
        #pragma unroll
        for (int gg = 0; gg < 4; ++gg) g4[gg] = MFMA16(aT[kc], bwD[gg][kc], g4[gg]);
      }
      if (lane < 16){
        #pragma unroll
        for (int j = 0; j < 4; ++j){
          float4 v0 = *(const float4*)&op_s[0][0];  // dummy init avoided; sum below
          (void)v0;
          float so = 0.f;
          #pragma unroll
          for (int w = 0; w < 8; ++w) so += op_s[w][j];
          float s0 = sum_s[j], s1 = sum_s[j+4];
          float yt = (s0*ps[j] + s1*ps[j+4]) * __builtin_amdgcn_rcpf((s0 + s1) * 256.f) + l1b0;
          float outp = (t == 0) ? 0.f : fast_sig(so + l3b0);
          yt += l1w0 * outp;
          float gi = g4[0][j] + bias_r[0] + wih_r[0]*yt;
          float gf = g4[1][j] + bias_r[1] + wih_r[1]*yt;
          float gg2 = g4[2][j] + bias_r[2] + wih_r[2]*yt;
          float go = g4[3][j] + bias_r[3] + wih_r[3]*yt;
          float cold = cds_r[j];
          float cn = fast_sig(gf)*cold + fast_sig(gi)*fast_tanh(gg2);
          float hn = fast_sig(go)*fast_tanh(cn);
          cds_r[j] = cn;
          sAB[j*264 + n16] = f2bf(hn);
          sAB[j*264 + 128 + n16] = f2bf(cn);
        }
      }
    }
    __syncthreads();  // 3

    // ---- F: o = [ct|d_new] @ l2W^T + l2b via MFMA; l3.o partials ----
    {
      f4v of = {0.f,0.f,0.f,0.f};
      #pragma unroll
      for (int kc = 0; kc < 4; ++kc){
        s8v af = *(const s8v*)((const char*)sCT + (lane&15)*272 + kc*64 + g*16);
        of = MFMA16(af, bwF[kc], of);
      }
      #pragma unroll
      for (int kc = 4; kc < 8; ++kc){
        s8v af = *(const s8v*)((const char*)sAB + (lane&15)*528 + (kc-4)*64 + g*16);
        of = MFMA16(af, bwF[kc], of);
      }
      float p0 = l3w_r*(of[0] + l2b_r);
      float p1 = l3w_r*(of[1] + l2b_r);
      float p2 = l3w_r*(of[2] + l2b_r);
      float p3 = l3w_r*(of[3] + l2b_r);
      #pragma unroll
      for (int off = 1; off <= 8; off <<= 1){
        p0 += __shfl_xor(p0, off, 64);
        p1 += __shfl_xor(p1, off, 64);
        p2 += __shfl_xor(p2, off, 64);
        p3 += __shfl_xor(p3, off, 64);
      }
      if (lane == 0){
        op_s[wave][0] = p0; op_s[wave][1] = p1;
        op_s[wave][2] = p2; op_s[wave][3] = p3;
      }
    }
    // no trailing barrier: op_s consumed after bar1+bar2 of t+1
  }
  __syncthreads();
  if (tid < 4){
    float s = 0.f;
    #pragma unroll
    for (int w = 0; w < 8; ++w) s += op_s[w][tid];
    out[bbase + tid] = fast_sig(s + l3b0);
  }
}

extern "C" void kernel_launch(void* const* d_in, const int* in_sizes, int n_in,
                              void* d_out, int out_size, void* d_ws, size_t ws_size,
                              hipStream_t stream){
  const float* X      = (const float*)d_in[0];
  const float* iaW1   = (const float*)d_in[1];
  const float* iab1   = (const float*)d_in[2];
  const float* iaW2   = (const float*)d_in[3];
  const float* encWih = (const float*)d_in[5];
  const float* encWhh = (const float*)d_in[6];
  const float* encbih = (const float*)d_in[7];
  const float* encbhh = (const float*)d_in[8];
  const float* taW1   = (const float*)d_in[9];
  const float* tab1   = (const float*)d_in[10];
  const float* taW2   = (const float*)d_in[11];
  const float* decWih = (const float*)d_in[13];
  const float* decWhh = (const float*)d_in[14];
  const float* decbih = (const float*)d_in[15];
  const float* decbhh = (const float*)d_in[16];
  const float* l1W    = (const float*)d_in[17];
  const float* l1b    = (const float*)d_in[18];
  const float* l2W    = (const float*)d_in[19];
  const float* l2b    = (const float*)d_in[20];
  const float* l3W    = (const float*)d_in[21];
  const float* l3b    = (const float*)d_in[22];

  char* ws = (char*)d_ws;
  uchar*  Eenc8 = (uchar*)(ws);                // 16MB fp8 coalesced; aliased by Edec8 later
  ushort* Hsb   = (ushort*)(ws + 33554432);    // 32MB bf16 [b][w][h]
  uchar*  HsT8  = (uchar*)(ws + 2*33554432);   // 16MB fp8 [b][h][w] (x16)
  uchar*  Edec8 = Eenc8;

  k_upre<<<dim3(2048), dim3(256), 0, stream>>>(X, iaW1, Eenc8);
  k_enc<<<dim3(512), dim3(512), 0, stream>>>(X, iaW1, iab1, iaW2,
                                             encWih, encWhh, encbih, encbhh,
                                             Eenc8, Hsb);
  k_vpre<<<dim3(2048), dim3(256), 0, stream>>>(Hsb, taW1, Edec8, HsT8);
  k_dec<<<dim3(512), dim3(512), 0, stream>>>(taW1, tab1, taW2,
                                             decWih, decWhh, decbih, decbhh,
                                             l1W, l1b, l2W, l2b, l3W, l3b,
                                             Edec8, HsT8, (float*)d_out);
}